// Round 5
// baseline (1019.964 us; speedup 1.0000x reference)
//
#include <hip/hip_runtime.h>

// Problem constants
#define BB   512
#define CC   22
#define TT   1000
#define HH   64
#define NCLS 4
#define RPB  16              // batch rows (MFMA cols) per block
#define NBLK (BB / RPB)      // 32 blocks
#define TC   25              // time steps staged per chunk (odd -> use global-t parity)
#define NCHUNK (TT / TC)     // 40
#define FCW  (TT * HH)       // 64000: W_fc row length

typedef _Float16 f16;
typedef __attribute__((ext_vector_type(2))) _Float16 h2;
typedef __attribute__((ext_vector_type(8))) _Float16 f16x8;
typedef __attribute__((ext_vector_type(4))) float    f32x4;

union U16x8 { uint4 q; f16x8 h; f16 e[8]; };

__device__ __forceinline__ float sigm(float x) {
    float e = __expf(-x);
    return __builtin_amdgcn_rcpf(1.0f + e);
}
__device__ __forceinline__ float tanh_(float x) {
    float e = __expf(-2.0f * fabsf(x));   // (0,1], no overflow
    float r = (1.0f - e) * __builtin_amdgcn_rcpf(1.0f + e);
    return copysignf(r, x);
}
__device__ __forceinline__ unsigned pack2(float a, float b) {
    union { unsigned u; h2 h; } c;
    c.h = h2{(f16)a, (f16)b};
    return c.u;
}

// R9 = R8 structure (MFMA layouts HW-verified by R8's passing absmax) with the
// recurrent critical path scrubbed of global-memory latency:
//  * R8 post-mortem: step time 2040 cyc, SIMDs ~85% stalled. Per-step W_fc
//    global loads (L2 evicted by the 45MB x stream -> L3-latency ~500-700cyc)
//    sat IN PROGRAM ORDER ahead of the h ds_write that all waves barrier-wait
//    on. Latency x barrier amplification = the stall.
//  * Fix 1: W_fc staged per-chunk into LDS (coalesced, amortized over TC
//    steps); per-step access = 4 broadcast ds_read_b128. Zero global ops in
//    the steady-state step.
//  * Fix 2: h published to LDS IMMEDIATELY after computation, before the FC
//    accumulation, so the barrier never queues behind anything.
//  * TC=50 -> 25 so xs + wfcs fit LDS; h-buffer parity now uses GLOBAL t.
__global__ __launch_bounds__(256, 1) void lstm_mfma2(
    const float* __restrict__ x,     // [B, C, T]
    const float* __restrict__ W_ih,  // [4H, C]
    const float* __restrict__ W_hh,  // [4H, H]
    const float* __restrict__ b_ih,  // [4H]
    const float* __restrict__ b_hh,  // [4H]
    const float* __restrict__ W_fc,  // [NCLS, T*H]
    const float* __restrict__ b_fc,  // [NCLS]
    float* __restrict__ out)         // [B, NCLS]
{
    __shared__ uint4 xs[TC * 64];                      // 25.6 KB: x B-fragments
    __shared__ __align__(16) float wfcs[TC][NCLS][HH]; // 25.6 KB: W_fc chunk
    __shared__ uint4 hb[2 * 128];                      // 4 KB: h dbuf, frag-linear
    __shared__ float fcp[4][RPB][NCLS];                // 1 KB: FC partial exchange

    const int tid   = threadIdx.x;
    const int w     = tid >> 6;      // wave: owns hids 16w..16w+15
    const int l     = tid & 63;
    const int c     = l & 15;        // batch col within block
    const int q     = l >> 4;
    const int hid0  = 16 * w + 4 * q;  // this lane's first hid
    const int rbase = blockIdx.x * RPB;

    // ---- one-time: A-fragments of W2 = [W_hh | W_ih | 0] + bias C-init ----
    f16x8 wA[4][3];                  // 4 gate-tiles x 3 K-tiles: 48 VGPR
    f32x4 biasf[4];
    #pragma unroll
    for (int g = 0; g < 4; ++g) {
        const int row = 64 * g + 16 * w + c;   // A row: m = lane&15
        const float* whr = W_hh + row * HH;
        const float* wir = W_ih + row * CC;
        #pragma unroll
        for (int kt = 0; kt < 3; ++kt) {
            U16x8 u;
            #pragma unroll
            for (int e = 0; e < 8; ++e) {
                const int k = 32 * kt + 8 * q + e;
                float v = 0.0f;
                if (k < HH) v = whr[k];
                else if (k < HH + CC) v = wir[k - HH];
                u.e[e] = (f16)v;
            }
            wA[g][kt] = u.h;
        }
        const float4 bi = *(const float4*)(b_ih + 64 * g + hid0);
        const float4 bh = *(const float4*)(b_hh + 64 * g + hid0);
        biasf[g][0] = bi.x + bh.x; biasf[g][1] = bi.y + bh.y;
        biasf[g][2] = bi.z + bh.z; biasf[g][3] = bi.w + bh.w;
    }
    #pragma unroll
    for (int g = 0; g < 4; ++g)
        #pragma unroll
        for (int kt = 0; kt < 3; ++kt)
            asm volatile("" : "+v"(wA[g][kt]));   // keep resident, no remat

    // h_0 = 0: zero both h buffers (256 slots, one per thread)
    hb[tid] = uint4{0u, 0u, 0u, 0u};

    float cst[4] = {0.f, 0.f, 0.f, 0.f};   // c for hids hid0..hid0+3, col c
    float fca[4] = {0.f, 0.f, 0.f, 0.f};   // FC partials, 4 classes

    // writer byte offset into an h buffer (constant per thread); layout
    // verified on HW by R8's passing absmax:
    const int woff = (w >> 1) * 1024 + (2 * (w & 1) + (q >> 1)) * 256
                   + c * 16 + (q & 1) * 8;

    for (int chunk = 0; chunk < NCHUNK; ++chunk) {
        const int T0 = chunk * TC;

        // ---- stage x chunk as B-fragments (frag-linear, zero-padded) ----
        // safe vs prev chunk: every wave's last reads precede its end-of-step
        // barrier at tt=TC-1.
        for (int s = tid; s < TC * 64; s += 256) {
            const int t  = s >> 6, sl = s & 63;
            const int sc = sl & 15, sq = sl >> 4;
            U16x8 u;
            if (sq == 3) {
                u.q = uint4{0u, 0u, 0u, 0u};           // k rows 88..95 = pad
            } else {
                const float* gx = x + (size_t)(rbase + sc) * (CC * TT) + T0 + t;
                #pragma unroll
                for (int e = 0; e < 8; ++e) {
                    const int ch = 8 * sq + e;
                    u.e[e] = (f16)(ch < CC ? gx[ch * TT] : 0.0f);
                }
            }
            xs[s] = u.q;
        }
        // ---- stage W_fc chunk (coalesced float4 loads) ----
        for (int s = tid; s < TC * NCLS * 16; s += 256) {
            const int t   = s >> 6;          // 64 float4-units per step
            const int cls = (s >> 4) & 3;
            const int f   = s & 15;
            const float4 v = *(const float4*)(W_fc + (size_t)cls * FCW
                                              + (size_t)(T0 + t) * HH + 4 * f);
            *(float4*)&wfcs[t][cls][4 * f] = v;
        }
        __syncthreads();   // publish xs + wfcs

        for (int tt = 0; tt < TC; ++tt) {
            const int tg = T0 + tt;
            const int rb = (tg & 1) * 128;   // h read buffer (global-t parity)

            // B-fragments: h (2 K-tiles) + x (1 K-tile), all linear reads
            U16x8 hx0, hx1, xb;
            hx0.q = hb[rb + l];
            hx1.q = hb[rb + 64 + l];
            xb.q  = xs[tt * 64 + l];

            // W_fc for this step from LDS (16-lane broadcast b128 reads)
            const float4 wf0 = *(const float4*)&wfcs[tt][0][hid0];
            const float4 wf1 = *(const float4*)&wfcs[tt][1][hid0];
            const float4 wf2 = *(const float4*)&wfcs[tt][2][hid0];
            const float4 wf3 = *(const float4*)&wfcs[tt][3][hid0];

            // 12 MFMA: gates for 16 rows, bias as C-init
            f32x4 d0 = __builtin_amdgcn_mfma_f32_16x16x32_f16(wA[0][0], hx0.h, biasf[0], 0, 0, 0);
            f32x4 d1 = __builtin_amdgcn_mfma_f32_16x16x32_f16(wA[1][0], hx0.h, biasf[1], 0, 0, 0);
            f32x4 d2 = __builtin_amdgcn_mfma_f32_16x16x32_f16(wA[2][0], hx0.h, biasf[2], 0, 0, 0);
            f32x4 d3 = __builtin_amdgcn_mfma_f32_16x16x32_f16(wA[3][0], hx0.h, biasf[3], 0, 0, 0);
            d0 = __builtin_amdgcn_mfma_f32_16x16x32_f16(wA[0][1], hx1.h, d0, 0, 0, 0);
            d1 = __builtin_amdgcn_mfma_f32_16x16x32_f16(wA[1][1], hx1.h, d1, 0, 0, 0);
            d2 = __builtin_amdgcn_mfma_f32_16x16x32_f16(wA[2][1], hx1.h, d2, 0, 0, 0);
            d3 = __builtin_amdgcn_mfma_f32_16x16x32_f16(wA[3][1], hx1.h, d3, 0, 0, 0);
            d0 = __builtin_amdgcn_mfma_f32_16x16x32_f16(wA[0][2], xb.h, d0, 0, 0, 0);
            d1 = __builtin_amdgcn_mfma_f32_16x16x32_f16(wA[1][2], xb.h, d1, 0, 0, 0);
            d2 = __builtin_amdgcn_mfma_f32_16x16x32_f16(wA[2][2], xb.h, d2, 0, 0, 0);
            d3 = __builtin_amdgcn_mfma_f32_16x16x32_f16(wA[3][2], xb.h, d3, 0, 0, 0);

            // lane-local LSTM update: 4 hids x 1 col per lane
            float h[4];
            #pragma unroll
            for (int r = 0; r < 4; ++r) {
                const float iv = sigm(d0[r]);
                const float fv = sigm(d1[r]);
                const float gv = tanh_(d2[r]);
                const float ov = sigm(d3[r]);
                cst[r] = fv * cst[r] + iv * gv;
                h[r] = ov * tanh_(cst[r]);
            }

            // publish h for t+1 FIRST -- nothing may queue ahead of this
            uint2 hp;
            hp.x = pack2(h[0], h[1]);
            hp.y = pack2(h[2], h[3]);
            *(uint2*)((char*)hb + ((tg + 1) & 1) * 2048 + woff) = hp;

            // FC accumulation (off the publish path)
            fca[0] += h[0] * wf0.x + h[1] * wf0.y + h[2] * wf0.z + h[3] * wf0.w;
            fca[1] += h[0] * wf1.x + h[1] * wf1.y + h[2] * wf1.z + h[3] * wf1.w;
            fca[2] += h[0] * wf2.x + h[1] * wf2.y + h[2] * wf2.z + h[3] * wf2.w;
            fca[3] += h[0] * wf3.x + h[1] * wf3.y + h[2] * wf3.z + h[3] * wf3.w;

            __syncthreads();
        }
    }

    // ---- FC reduce: over q-groups (shuffle), then over waves (LDS) ----
    #pragma unroll
    for (int k = 0; k < 4; ++k) {
        fca[k] += __shfl_xor(fca[k], 16);
        fca[k] += __shfl_xor(fca[k], 32);
    }
    if (q == 0) {
        #pragma unroll
        for (int k = 0; k < 4; ++k) fcp[w][c][k] = fca[k];
    }
    __syncthreads();
    if (w == 0 && l < 16) {
        float lg[4];
        #pragma unroll
        for (int k = 0; k < 4; ++k)
            lg[k] = fcp[0][l][k] + fcp[1][l][k] + fcp[2][l][k] + fcp[3][l][k]
                  + b_fc[k];
        const float m  = fmaxf(fmaxf(lg[0], lg[1]), fmaxf(lg[2], lg[3]));
        const float e0 = __expf(lg[0] - m), e1 = __expf(lg[1] - m);
        const float e2 = __expf(lg[2] - m), e3 = __expf(lg[3] - m);
        const float is = __builtin_amdgcn_rcpf(e0 + e1 + e2 + e3);
        float4 o; o.x = e0 * is; o.y = e1 * is; o.z = e2 * is; o.w = e3 * is;
        *(float4*)(out + (rbase + l) * NCLS) = o;
    }
}

extern "C" void kernel_launch(void* const* d_in, const int* in_sizes, int n_in,
                              void* d_out, int out_size, void* d_ws, size_t ws_size,
                              hipStream_t stream) {
    const float* x    = (const float*)d_in[0];
    const float* W_ih = (const float*)d_in[1];
    const float* W_hh = (const float*)d_in[2];
    const float* b_ih = (const float*)d_in[3];
    const float* b_hh = (const float*)d_in[4];
    const float* W_fc = (const float*)d_in[5];
    const float* b_fc = (const float*)d_in[6];
    float* out = (float*)d_out;

    lstm_mfma2<<<NBLK, 256, 0, stream>>>(x, W_ih, W_hh, b_ih, b_hh, W_fc, b_fc, out);
}

// Round 6
// 945.126 us; speedup vs baseline: 1.0792x; 1.0792x over previous
//
#include <hip/hip_runtime.h>

// Problem constants
#define BB   512
#define CC   22
#define TT   1000
#define HH   64
#define NCLS 4
#define RPB  16              // batch rows (MFMA cols) per block
#define NBLK (BB / RPB)      // 32 blocks
#define TC   25              // time steps staged per chunk
#define NCHUNK (TT / TC)     // 40
#define FCW  (TT * HH)       // 64000: W_fc row length
#define NREAL (TC * 48)      // real xs slots per chunk (q=3 slots are static 0)
#define PFS  5               // ceil(NREAL / 256) prefetch slots per thread

typedef _Float16 f16;
typedef __attribute__((ext_vector_type(2))) _Float16 h2;
typedef __attribute__((ext_vector_type(8))) _Float16 f16x8;
typedef __attribute__((ext_vector_type(4))) float    f32x4;

union U16x8 { uint4 q; f16x8 h; f16 e[8]; };

__device__ __forceinline__ float sigm(float x) {
    float e = __expf(-x);
    return __builtin_amdgcn_rcpf(1.0f + e);
}
__device__ __forceinline__ float tanh_(float x) {
    float e = __expf(-2.0f * fabsf(x));   // (0,1], no overflow
    float r = (1.0f - e) * __builtin_amdgcn_rcpf(1.0f + e);
    return copysignf(r, x);
}
__device__ __forceinline__ unsigned pack2(float a, float b) {
    union { unsigned u; h2 h; } c;
    c.h = h2{(f16)a, (f16)b};
    return c.u;
}

// R10: R8/R9 MFMA structure (layouts HW-verified by their passing absmax) with
// the per-step __syncthreads REPLACED by an LDS spin-counter sync.
//
// Evidence: every barrier-per-step structure (R5 fdot2-split, R8/R9 MFMA)
// carries a ~900-1100 cyc/step constant the barrier-free R4 doesn't pay, and
// R9 proved it is NOT global-load latency (zero VMEM in its loop; step got
// slower). __syncthreads = full vmcnt+lgkm drain + 4-wave s_barrier release
// under 1-wave/SIMD occupancy. The spin sync costs ~write-ack + observe
// (~300 cyc) and never drains vmcnt, so global W_fc / x-prefetch loads stay
// in flight across steps.
//
// Soundness of the spin sync:
//  * publish->signal: h ds_write, then asm lgkmcnt(0), then one ds_add per
//    wave. In-order DS pipe + explicit ack => any wave observing the count
//    sees the h data.
//  * read-before-overwrite: h is double-buffered by t-parity. A wave writes
//    buf[t&1] (as h for t+1) only after passing sync t-1... concretely:
//    arrival at sync t requires that wave already READ buf[t&1] this step;
//    the next write to buf[t&1] happens in step t+1, after sync t released,
//    i.e. after ALL waves read it. No race.
//  * uniform sync count (1000 steps + 40 chunk bounds + prologue barrier);
//    4 waves on 4 SIMDs, all resident => forward progress guaranteed.
//
// Staging: x gathers for chunk+1 are issued into REGISTERS at chunk start
// (PFS*8 = 40 scattered dwords/thread, latency hidden under 25 steps of
// compute), packed+committed to the other xs buffer at chunk end. W_fc is
// register-rotated one step ahead. q=3 fragment slots are zeroed once.
__global__ __launch_bounds__(256, 1) void lstm_spin(
    const float* __restrict__ x,     // [B, C, T]
    const float* __restrict__ W_ih,  // [4H, C]
    const float* __restrict__ W_hh,  // [4H, H]
    const float* __restrict__ b_ih,  // [4H]
    const float* __restrict__ b_hh,  // [4H]
    const float* __restrict__ W_fc,  // [NCLS, T*H]
    const float* __restrict__ b_fc,  // [NCLS]
    float* __restrict__ out)         // [B, NCLS]
{
    __shared__ uint4 xs[2 * TC * 64];      // 51.2 KB: x B-fragments, dbuf
    __shared__ uint4 hb[2 * 128];          // 4 KB: h B-fragments, dbuf
    __shared__ float fcp[4][RPB][NCLS];    // 1 KB: FC partial exchange
    __shared__ int   cnt;                  // spin-sync counter (monotonic)

    const int tid   = threadIdx.x;
    const int w     = tid >> 6;      // wave: owns hids 16w..16w+15
    const int l     = tid & 63;
    const int c     = l & 15;        // batch col within block
    const int q     = l >> 4;
    const int hid0  = 16 * w + 4 * q;
    const int rbase = blockIdx.x * RPB;

    // ---- one-time: A-fragments of [W_hh | W_ih | 0] + bias C-init ----
    f16x8 wA[4][3];
    f32x4 biasf[4];
    #pragma unroll
    for (int g = 0; g < 4; ++g) {
        const int row = 64 * g + 16 * w + c;
        const float* whr = W_hh + row * HH;
        const float* wir = W_ih + row * CC;
        #pragma unroll
        for (int kt = 0; kt < 3; ++kt) {
            U16x8 u;
            #pragma unroll
            for (int e = 0; e < 8; ++e) {
                const int k = 32 * kt + 8 * q + e;
                float v = 0.0f;
                if (k < HH) v = whr[k];
                else if (k < HH + CC) v = wir[k - HH];
                u.e[e] = (f16)v;
            }
            wA[g][kt] = u.h;
        }
        const float4 bi = *(const float4*)(b_ih + 64 * g + hid0);
        const float4 bh = *(const float4*)(b_hh + 64 * g + hid0);
        biasf[g][0] = bi.x + bh.x; biasf[g][1] = bi.y + bh.y;
        biasf[g][2] = bi.z + bh.z; biasf[g][3] = bi.w + bh.w;
    }
    #pragma unroll
    for (int g = 0; g < 4; ++g)
        #pragma unroll
        for (int kt = 0; kt < 3; ++kt)
            asm volatile("" : "+v"(wA[g][kt]));

    // ---- prologue: counter, static zeros, chunk-0 stage, W_fc step-0 ----
    if (tid == 0) cnt = 0;
    for (int s = tid; s < 2 * TC * 64; s += 256)
        if ((s & 63) >= 48) xs[s] = uint4{0u, 0u, 0u, 0u};   // q=3 pad, static
    hb[tid] = uint4{0u, 0u, 0u, 0u};                          // h_0 = 0 (both bufs)

    float pfx[PFS][8];
    // gather chunk 0 into regs (same math as the per-chunk prefetch below)
    #pragma unroll
    for (int i = 0; i < PFS; ++i) {
        const int s = tid + i * 256;
        if (s < NREAL) {
            const int t  = s / 48, sl = s - 48 * t;
            const int sc = sl & 15, sq = sl >> 4;          // sq in 0..2
            const float* gx = x + (size_t)(rbase + sc) * (CC * TT)
                                + (size_t)(8 * sq) * TT + t;
            #pragma unroll
            for (int e = 0; e < 8; ++e)
                pfx[i][e] = (8 * sq + e < CC) ? gx[e * TT] : 0.0f;
        }
    }
    // commit chunk 0 into buffer 0
    #pragma unroll
    for (int i = 0; i < PFS; ++i) {
        const int s = tid + i * 256;
        if (s < NREAL) {
            const int t = s / 48, sl = s - 48 * t;
            U16x8 u;
            #pragma unroll
            for (int e = 0; e < 8; ++e) u.e[e] = (f16)pfx[i][e];
            xs[t * 64 + sl] = u.q;
        }
    }
    // W_fc for step 0
    float4 wfc0, wfc1, wfc2, wfc3;
    {
        const float* wp = W_fc + hid0;
        wfc0 = *(const float4*)(wp);
        wfc1 = *(const float4*)(wp + FCW);
        wfc2 = *(const float4*)(wp + 2 * FCW);
        wfc3 = *(const float4*)(wp + 3 * FCW);
    }
    __syncthreads();   // one real barrier: publishes cnt=0, zeros, chunk 0

    float cst[4] = {0.f, 0.f, 0.f, 0.f};
    float fca[4] = {0.f, 0.f, 0.f, 0.f};
    int epoch = 0;

    const int woff = (w >> 1) * 1024 + (2 * (w & 1) + (q >> 1)) * 256
                   + c * 16 + (q & 1) * 8;

    for (int chunk = 0; chunk < NCHUNK; ++chunk) {
        const int T0 = chunk * TC;

        // ---- issue next chunk's x gathers into regs (hidden under steps) ----
        if (chunk + 1 < NCHUNK) {
            const int Tn = T0 + TC;
            #pragma unroll
            for (int i = 0; i < PFS; ++i) {
                const int s = tid + i * 256;
                if (s < NREAL) {
                    const int t  = s / 48, sl = s - 48 * t;
                    const int sc = sl & 15, sq = sl >> 4;
                    const float* gx = x + (size_t)(rbase + sc) * (CC * TT)
                                        + (size_t)(8 * sq) * TT + Tn + t;
                    #pragma unroll
                    for (int e = 0; e < 8; ++e)
                        pfx[i][e] = (8 * sq + e < CC) ? gx[e * TT] : 0.0f;
                }
            }
        }

        for (int tt = 0; tt < TC; ++tt) {
            const int tg = T0 + tt;
            const int rb = (tg & 1) * 128;

            // W_fc prefetch for NEXT step (consumed next iteration)
            const int tn = (tg + 1 < TT) ? tg + 1 : tg;
            const float* wp = W_fc + tn * HH + hid0;
            float4 wfn0 = *(const float4*)(wp);
            float4 wfn1 = *(const float4*)(wp + FCW);
            float4 wfn2 = *(const float4*)(wp + 2 * FCW);
            float4 wfn3 = *(const float4*)(wp + 3 * FCW);

            // B-fragments: h (2 K-tiles) + x (1 K-tile)
            U16x8 hx0, hx1, xb;
            hx0.q = hb[rb + l];
            hx1.q = hb[rb + 64 + l];
            xb.q  = xs[(chunk & 1) * (TC * 64) + tt * 64 + l];

            // 12 MFMA: gates for 16 rows, bias as C-init
            f32x4 d0 = __builtin_amdgcn_mfma_f32_16x16x32_f16(wA[0][0], hx0.h, biasf[0], 0, 0, 0);
            f32x4 d1 = __builtin_amdgcn_mfma_f32_16x16x32_f16(wA[1][0], hx0.h, biasf[1], 0, 0, 0);
            f32x4 d2 = __builtin_amdgcn_mfma_f32_16x16x32_f16(wA[2][0], hx0.h, biasf[2], 0, 0, 0);
            f32x4 d3 = __builtin_amdgcn_mfma_f32_16x16x32_f16(wA[3][0], hx0.h, biasf[3], 0, 0, 0);
            d0 = __builtin_amdgcn_mfma_f32_16x16x32_f16(wA[0][1], hx1.h, d0, 0, 0, 0);
            d1 = __builtin_amdgcn_mfma_f32_16x16x32_f16(wA[1][1], hx1.h, d1, 0, 0, 0);
            d2 = __builtin_amdgcn_mfma_f32_16x16x32_f16(wA[2][1], hx1.h, d2, 0, 0, 0);
            d3 = __builtin_amdgcn_mfma_f32_16x16x32_f16(wA[3][1], hx1.h, d3, 0, 0, 0);
            d0 = __builtin_amdgcn_mfma_f32_16x16x32_f16(wA[0][2], xb.h, d0, 0, 0, 0);
            d1 = __builtin_amdgcn_mfma_f32_16x16x32_f16(wA[1][2], xb.h, d1, 0, 0, 0);
            d2 = __builtin_amdgcn_mfma_f32_16x16x32_f16(wA[2][2], xb.h, d2, 0, 0, 0);
            d3 = __builtin_amdgcn_mfma_f32_16x16x32_f16(wA[3][2], xb.h, d3, 0, 0, 0);

            // lane-local LSTM update: 4 hids x 1 col per lane
            float h[4];
            #pragma unroll
            for (int r = 0; r < 4; ++r) {
                const float iv = sigm(d0[r]);
                const float fv = sigm(d1[r]);
                const float gv = tanh_(d2[r]);
                const float ov = sigm(d3[r]);
                cst[r] = fv * cst[r] + iv * gv;
                h[r] = ov * tanh_(cst[r]);
            }

            // publish h for t+1 (other buffer)
            uint2 hp;
            hp.x = pack2(h[0], h[1]);
            hp.y = pack2(h[2], h[3]);
            *(uint2*)((char*)hb + ((tg + 1) & 1) * 2048 + woff) = hp;

            // FC accumulation with the pre-fetched (arrived) W_fc of step tg
            fca[0] += h[0] * wfc0.x + h[1] * wfc0.y + h[2] * wfc0.z + h[3] * wfc0.w;
            fca[1] += h[0] * wfc1.x + h[1] * wfc1.y + h[2] * wfc1.z + h[3] * wfc1.w;
            fca[2] += h[0] * wfc2.x + h[1] * wfc2.y + h[2] * wfc2.z + h[3] * wfc2.w;
            fca[3] += h[0] * wfc3.x + h[1] * wfc3.y + h[2] * wfc3.z + h[3] * wfc3.w;
            wfc0 = wfn0; wfc1 = wfn1; wfc2 = wfn2; wfc3 = wfn3;

            // ---- spin sync (no vmcnt drain) ----
            asm volatile("s_waitcnt lgkmcnt(0)" ::: "memory");  // h write ack
            if (l == 0)
                __hip_atomic_fetch_add(&cnt, 1, __ATOMIC_RELAXED,
                                       __HIP_MEMORY_SCOPE_WORKGROUP);
            ++epoch;
            while (__hip_atomic_load(&cnt, __ATOMIC_RELAXED,
                                     __HIP_MEMORY_SCOPE_WORKGROUP) < 4 * epoch) {}
            asm volatile("" ::: "memory");
        }

        // ---- commit next chunk's x into the other buffer ----
        if (chunk + 1 < NCHUNK) {
            const int base = ((chunk + 1) & 1) * (TC * 64);
            #pragma unroll
            for (int i = 0; i < PFS; ++i) {
                const int s = tid + i * 256;
                if (s < NREAL) {
                    const int t = s / 48, sl = s - 48 * t;
                    U16x8 u;
                    #pragma unroll
                    for (int e = 0; e < 8; ++e) u.e[e] = (f16)pfx[i][e];
                    xs[base + t * 64 + sl] = u.q;
                }
            }
        }
        // chunk-boundary sync: commit visible before next chunk's reads
        asm volatile("s_waitcnt lgkmcnt(0)" ::: "memory");
        if (l == 0)
            __hip_atomic_fetch_add(&cnt, 1, __ATOMIC_RELAXED,
                                   __HIP_MEMORY_SCOPE_WORKGROUP);
        ++epoch;
        while (__hip_atomic_load(&cnt, __ATOMIC_RELAXED,
                                 __HIP_MEMORY_SCOPE_WORKGROUP) < 4 * epoch) {}
        asm volatile("" ::: "memory");
    }

    // ---- FC reduce: over q-groups (shuffle), then over waves (LDS) ----
    #pragma unroll
    for (int k = 0; k < 4; ++k) {
        fca[k] += __shfl_xor(fca[k], 16);
        fca[k] += __shfl_xor(fca[k], 32);
    }
    if (q == 0) {
        #pragma unroll
        for (int k = 0; k < 4; ++k) fcp[w][c][k] = fca[k];
    }
    __syncthreads();
    if (w == 0 && l < 16) {
        float lg[4];
        #pragma unroll
        for (int k = 0; k < 4; ++k)
            lg[k] = fcp[0][l][k] + fcp[1][l][k] + fcp[2][l][k] + fcp[3][l][k]
                  + b_fc[k];
        const float m  = fmaxf(fmaxf(lg[0], lg[1]), fmaxf(lg[2], lg[3]));
        const float e0 = __expf(lg[0] - m), e1 = __expf(lg[1] - m);
        const float e2 = __expf(lg[2] - m), e3 = __expf(lg[3] - m);
        const float is = __builtin_amdgcn_rcpf(e0 + e1 + e2 + e3);
        float4 o; o.x = e0 * is; o.y = e1 * is; o.z = e2 * is; o.w = e3 * is;
        *(float4*)(out + (rbase + l) * NCLS) = o;
    }
}

extern "C" void kernel_launch(void* const* d_in, const int* in_sizes, int n_in,
                              void* d_out, int out_size, void* d_ws, size_t ws_size,
                              hipStream_t stream) {
    const float* x    = (const float*)d_in[0];
    const float* W_ih = (const float*)d_in[1];
    const float* W_hh = (const float*)d_in[2];
    const float* b_ih = (const float*)d_in[3];
    const float* b_hh = (const float*)d_in[4];
    const float* W_fc = (const float*)d_in[5];
    const float* b_fc = (const float*)d_in[6];
    float* out = (float*)d_out;

    lstm_spin<<<NBLK, 256, 0, stream>>>(x, W_ih, W_hh, b_ih, b_hh, W_fc, b_fc, out);
}

// Round 7
// 729.548 us; speedup vs baseline: 1.3981x; 1.2955x over previous
//
#include <hip/hip_runtime.h>

// Problem constants
#define BB   512
#define CC   22
#define TT   1000
#define HH   64
#define NCLS 4
#define FCW  (TT * HH)       // 64000: W_fc row length
#define TB   100             // t-tile per xproj block (10 tiles)

typedef _Float16 f16;
typedef __attribute__((ext_vector_type(2))) _Float16 h2;

__device__ __forceinline__ float sigm(float x) {
    float e = __expf(-x);
    return __builtin_amdgcn_rcpf(1.0f + e);
}
__device__ __forceinline__ float tanh_(float x) {
    float e = __expf(-2.0f * fabsf(x));   // (0,1], no overflow
    float r = (1.0f - e) * __builtin_amdgcn_rcpf(1.0f + e);
    return copysignf(r, x);
}
__device__ __forceinline__ h2 u2h(unsigned u) {
    union { unsigned u; h2 h; } c; c.u = u; return c.h;
}
__device__ __forceinline__ unsigned h2u(h2 h) {
    union { unsigned u; h2 h; } c; c.h = h; return c.u;
}

// ---------------------------------------------------------------------------
// R11 kernel 1: x-projection precompute.
//   xp[b][t][hid][gate] (f16) = b_ih[g*64+hid] + b_hh[..] + sum_c W_ih[..][c]*x[b][c][t]
// Thread tid <-> (hid = tid>>2, g = tid&3) so the f16 store index is exactly
// tid -> fully coalesced 512B stores. x tile staged in LDS; inner loop reads
// float4 of 4 consecutive t (broadcast b128) -> 1 ds_read + 4 fmac per channel.
// ---------------------------------------------------------------------------
__global__ __launch_bounds__(256) void xproj(
    const float* __restrict__ x,     // [B, C, T]
    const float* __restrict__ W_ih,  // [4H, C]
    const float* __restrict__ b_ih,  // [4H]
    const float* __restrict__ b_hh,  // [4H]
    f16* __restrict__ xp)            // [B, T, H, 4]
{
    __shared__ __align__(16) float xt[CC][TB];   // 8.8 KB

    const int tid = threadIdx.x;
    const int t0  = blockIdx.x * TB;
    const int b   = blockIdx.y;
    const int hid = tid >> 2;
    const int g   = tid & 3;
    const int row = g * HH + hid;

    // stage x[b][:, t0..t0+TB) -- coalesced along t
    for (int s = tid; s < CC * TB; s += 256) {
        const int c = s / TB, t = s - c * TB;
        xt[c][t] = x[((size_t)b * CC + c) * TT + t0 + t];
    }
    // this thread's W_ih row + folded bias
    float wr[CC];
    #pragma unroll
    for (int c = 0; c < CC; ++c) wr[c] = W_ih[row * CC + c];
    const float bias = b_ih[row] + b_hh[row];
    __syncthreads();

    f16* op = xp + ((size_t)b * TT + t0) * 256 + tid;   // 256 f16 per (b,t)
    for (int t = 0; t < TB; t += 4) {
        float a0 = bias, a1 = bias, a2 = bias, a3 = bias;
        #pragma unroll
        for (int c = 0; c < CC; ++c) {
            const float4 xv = *(const float4*)&xt[c][t];   // broadcast
            a0 += wr[c] * xv.x; a1 += wr[c] * xv.y;
            a2 += wr[c] * xv.z; a3 += wr[c] * xv.w;
        }
        op[0]   = (f16)a0;
        op[256] = (f16)a1;
        op[512] = (f16)a2;
        op[768] = (f16)a3;
        op += 1024;
    }
}

// ---------------------------------------------------------------------------
// R11 kernel 2: lean single-wave recurrence (R4 structure, zero barriers).
// Changes vs R4 (640us):
//  * x-part of the gates precomputed (kernel 1): 44 fdot2 + LDS x-staging +
//    bias regs replaced by ONE coalesced uint2 load/step, consumed at the END
//    of the gate accumulation so its latency hides under the 256-cyc h-dot.
//  * amdgpu_waves_per_eu(1,1): R4's VGPR_Count=132 < its 176 pinned weights
//    proved the allocator parked ~100 weights in AGPRs and paid ~350 cyc/step
//    of v_accvgpr_read. With an explicit 1-wave/EU bound the budget is 512
//    regs -> whh (128) + working set (~60) are true VGPRs, tax gone.
// Step model: 128 fdot2 (256cyc) + acts ~56 + misc ~70 + h-LDS RT ~120
//             ~= 550 cyc -> ~230us for the 1000-step chain.
// ---------------------------------------------------------------------------
__global__ __attribute__((amdgpu_waves_per_eu(1, 1)))
__launch_bounds__(64) void lstm_rec(
    const uint2* __restrict__ xp,    // [B, T, H] as uint2 (4 f16 gates)
    const float* __restrict__ W_hh,  // [4H, H]
    const float* __restrict__ W_fc,  // [NCLS, T*H]
    const float* __restrict__ b_fc,  // [NCLS]
    float* __restrict__ out)         // [B, NCLS]
{
    __shared__ __align__(16) f16 hbuf[HH];   // 128 B: h broadcast

    const int lane = threadIdx.x;    // hidden unit
    const int r    = blockIdx.x;     // batch row

    // per-lane recurrent weights (128 VGPR), pinned resident
    unsigned whh[4][32];
    #pragma unroll
    for (int g = 0; g < 4; ++g) {
        const float* wr = W_hh + (g * HH + lane) * HH;
        #pragma unroll
        for (int k = 0; k < 32; ++k)
            whh[g][k] = h2u(h2{(f16)wr[2 * k], (f16)wr[2 * k + 1]});
    }
    #pragma unroll
    for (int g = 0; g < 4; ++g)
        #pragma unroll
        for (int k = 0; k < 32; ++k) asm volatile("" : "+v"(whh[g][k]));

    hbuf[lane] = (f16)0.0f;          // own-wave in-order DS; no barrier
    float c = 0.0f;
    float fc0 = 0.f, fc1 = 0.f, fc2 = 0.f, fc3 = 0.f;
    const uint2* px = xp + (size_t)r * TT * HH + lane;
    const float* p0 = W_fc + 0 * FCW + lane;
    const float* p1 = W_fc + 1 * FCW + lane;
    const float* p2 = W_fc + 2 * FCW + lane;
    const float* p3 = W_fc + 3 * FCW + lane;

    for (int t = 0; t < TT; ++t) {
        // global loads first; consumed at the very end of the step -> hidden
        const uint2 xv = px[(size_t)t * HH];
        const float w0 = *p0, w1 = *p1, w2 = *p2, w3 = *p3;
        p0 += HH; p1 += HH; p2 += HH; p3 += HH;

        // h broadcast (8 x ds_read_b128, all lanes same address)
        union { uint4 q[8]; h2 h[32]; } H;
        const uint4* hr = (const uint4*)hbuf;
        #pragma unroll
        for (int i = 0; i < 8; ++i) H.q[i] = hr[i];

        // 4 gate dots over h (128 fdot2)
        float a0 = 0.f, a1 = 0.f, a2 = 0.f, a3 = 0.f;
        #pragma unroll
        for (int k = 0; k < 32; ++k) {
            a0 = __builtin_amdgcn_fdot2(H.h[k], u2h(whh[0][k]), a0, false);
            a1 = __builtin_amdgcn_fdot2(H.h[k], u2h(whh[1][k]), a1, false);
            a2 = __builtin_amdgcn_fdot2(H.h[k], u2h(whh[2][k]), a2, false);
            a3 = __builtin_amdgcn_fdot2(H.h[k], u2h(whh[3][k]), a3, false);
        }
        // add precomputed x-projection (+bias), f16 -> f32
        const h2 pif = u2h(xv.x), pgo = u2h(xv.y);
        a0 += (float)pif[0]; a1 += (float)pif[1];
        a2 += (float)pgo[0]; a3 += (float)pgo[1];

        // lane-local LSTM update
        const float iv = sigm(a0), fv = sigm(a1);
        const float gv = tanh_(a2), ov = sigm(a3);
        c = fv * c + iv * gv;
        const float h = ov * tanh_(c);

        // fused FC accumulation
        fc0 += h * w0; fc1 += h * w1; fc2 += h * w2; fc3 += h * w3;

        // publish h for next step (own-wave LDS, in-order DS pipe)
        hbuf[lane] = (f16)h;
    }

    // FC reduce over hid (wave shuffle) + softmax
    #pragma unroll
    for (int off = 32; off; off >>= 1) {
        fc0 += __shfl_down(fc0, off);
        fc1 += __shfl_down(fc1, off);
        fc2 += __shfl_down(fc2, off);
        fc3 += __shfl_down(fc3, off);
    }
    if (lane == 0) {
        const float l0 = fc0 + b_fc[0], l1 = fc1 + b_fc[1];
        const float l2 = fc2 + b_fc[2], l3 = fc3 + b_fc[3];
        const float m  = fmaxf(fmaxf(l0, l1), fmaxf(l2, l3));
        const float e0 = __expf(l0 - m), e1 = __expf(l1 - m);
        const float e2 = __expf(l2 - m), e3 = __expf(l3 - m);
        const float is = __builtin_amdgcn_rcpf(e0 + e1 + e2 + e3);
        float4 o; o.x = e0 * is; o.y = e1 * is; o.z = e2 * is; o.w = e3 * is;
        *(float4*)(out + r * NCLS) = o;
    }
}

// ---------------------------------------------------------------------------
// Fallback: R4's self-contained kernel (known-good 640us) + waves_per_eu fix,
// used only if the workspace can't hold xp (262 MB).
// ---------------------------------------------------------------------------
#define TC   250
#define NCHUNK (TT / TC)
#define XROW 12

__global__ __attribute__((amdgpu_waves_per_eu(1, 1)))
__launch_bounds__(64) void lstm_fb(
    const float* __restrict__ x, const float* __restrict__ W_ih,
    const float* __restrict__ W_hh, const float* __restrict__ b_ih,
    const float* __restrict__ b_hh, const float* __restrict__ W_fc,
    const float* __restrict__ b_fc, float* __restrict__ out)
{
    __shared__ __align__(16) h2  xs[TC][XROW];
    __shared__ __align__(16) f16 hbuf[HH];

    const int lane = threadIdx.x;
    const int r    = blockIdx.x;

    unsigned whh[4][32];
    unsigned wih[4][11];
    float bias[4];
    #pragma unroll
    for (int g = 0; g < 4; ++g) {
        const int row = g * HH + lane;
        const float* wr = W_hh + row * HH;
        #pragma unroll
        for (int k = 0; k < 32; ++k)
            whh[g][k] = h2u(h2{(f16)wr[2 * k], (f16)wr[2 * k + 1]});
        const float* wi = W_ih + row * CC;
        #pragma unroll
        for (int k = 0; k < 11; ++k)
            wih[g][k] = h2u(h2{(f16)wi[2 * k], (f16)wi[2 * k + 1]});
        bias[g] = b_ih[row] + b_hh[row];
    }
    #pragma unroll
    for (int g = 0; g < 4; ++g) {
        #pragma unroll
        for (int k = 0; k < 32; ++k) asm volatile("" : "+v"(whh[g][k]));
        #pragma unroll
        for (int k = 0; k < 11; ++k) asm volatile("" : "+v"(wih[g][k]));
        asm volatile("" : "+v"(bias[g]));
    }

    hbuf[lane] = (f16)0.0f;
    float c = 0.0f;
    float fc0 = 0.f, fc1 = 0.f, fc2 = 0.f, fc3 = 0.f;
    const float* p0 = W_fc + 0 * FCW + lane;
    const float* p1 = W_fc + 1 * FCW + lane;
    const float* p2 = W_fc + 2 * FCW + lane;
    const float* p3 = W_fc + 3 * FCW + lane;
    const float* xrow = x + (size_t)r * (CC * TT);

    for (int chunk = 0; chunk < NCHUNK; ++chunk) {
        for (int tb = 0; tb < TC; tb += 64) {
            const int t = tb + lane;
            if (t < TC) {
                const float* gx = xrow + chunk * TC + t;
                union { h2 h[XROW]; uint4 q[3]; } U;
                #pragma unroll
                for (int k = 0; k < 11; ++k)
                    U.h[k] = h2{(f16)gx[(2 * k) * TT], (f16)gx[(2 * k + 1) * TT]};
                U.h[11] = h2{(f16)0.0f, (f16)0.0f};
                uint4* dst = (uint4*)&xs[t][0];
                dst[0] = U.q[0]; dst[1] = U.q[1]; dst[2] = U.q[2];
            }
        }
        for (int tt = 0; tt < TC; ++tt) {
            union { uint4 q[8]; h2 h[32]; } H;
            const uint4* hr = (const uint4*)hbuf;
            #pragma unroll
            for (int i = 0; i < 8; ++i) H.q[i] = hr[i];
            union { uint4 q[3]; h2 h[XROW]; } X;
            const uint4* xr = (const uint4*)&xs[tt][0];
            X.q[0] = xr[0]; X.q[1] = xr[1]; X.q[2] = xr[2];
            float w0 = *p0, w1 = *p1, w2 = *p2, w3 = *p3;
            p0 += HH; p1 += HH; p2 += HH; p3 += HH;
            float a0 = bias[0], a1 = bias[1], a2 = bias[2], a3 = bias[3];
            #pragma unroll
            for (int k = 0; k < 11; ++k) {
                a0 = __builtin_amdgcn_fdot2(X.h[k], u2h(wih[0][k]), a0, false);
                a1 = __builtin_amdgcn_fdot2(X.h[k], u2h(wih[1][k]), a1, false);
                a2 = __builtin_amdgcn_fdot2(X.h[k], u2h(wih[2][k]), a2, false);
                a3 = __builtin_amdgcn_fdot2(X.h[k], u2h(wih[3][k]), a3, false);
            }
            #pragma unroll
            for (int k = 0; k < 32; ++k) {
                a0 = __builtin_amdgcn_fdot2(H.h[k], u2h(whh[0][k]), a0, false);
                a1 = __builtin_amdgcn_fdot2(H.h[k], u2h(whh[1][k]), a1, false);
                a2 = __builtin_amdgcn_fdot2(H.h[k], u2h(whh[2][k]), a2, false);
                a3 = __builtin_amdgcn_fdot2(H.h[k], u2h(whh[3][k]), a3, false);
            }
            const float iv = sigm(a0), fv = sigm(a1);
            const float gv = tanh_(a2), ov = sigm(a3);
            c = fv * c + iv * gv;
            const float h = ov * tanh_(c);
            fc0 += h * w0; fc1 += h * w1; fc2 += h * w2; fc3 += h * w3;
            hbuf[lane] = (f16)h;
        }
    }
    #pragma unroll
    for (int off = 32; off; off >>= 1) {
        fc0 += __shfl_down(fc0, off);
        fc1 += __shfl_down(fc1, off);
        fc2 += __shfl_down(fc2, off);
        fc3 += __shfl_down(fc3, off);
    }
    if (lane == 0) {
        const float l0 = fc0 + b_fc[0], l1 = fc1 + b_fc[1];
        const float l2 = fc2 + b_fc[2], l3 = fc3 + b_fc[3];
        const float m  = fmaxf(fmaxf(l0, l1), fmaxf(l2, l3));
        const float e0 = __expf(l0 - m), e1 = __expf(l1 - m);
        const float e2 = __expf(l2 - m), e3 = __expf(l3 - m);
        const float is = __builtin_amdgcn_rcpf(e0 + e1 + e2 + e3);
        float4 o; o.x = e0 * is; o.y = e1 * is; o.z = e2 * is; o.w = e3 * is;
        *(float4*)(out + r * NCLS) = o;
    }
}

extern "C" void kernel_launch(void* const* d_in, const int* in_sizes, int n_in,
                              void* d_out, int out_size, void* d_ws, size_t ws_size,
                              hipStream_t stream) {
    const float* x    = (const float*)d_in[0];
    const float* W_ih = (const float*)d_in[1];
    const float* W_hh = (const float*)d_in[2];
    const float* b_ih = (const float*)d_in[3];
    const float* b_hh = (const float*)d_in[4];
    const float* W_fc = (const float*)d_in[5];
    const float* b_fc = (const float*)d_in[6];
    float* out = (float*)d_out;

    const size_t need = (size_t)BB * TT * HH * 4 * sizeof(f16);   // 262.1 MB
    if (d_ws != nullptr && ws_size >= need) {
        f16* xp = (f16*)d_ws;
        xproj<<<dim3(TT / TB, BB), 256, 0, stream>>>(x, W_ih, b_ih, b_hh, xp);
        lstm_rec<<<BB, 64, 0, stream>>>((const uint2*)xp, W_hh, W_fc, b_fc, out);
    } else {
        lstm_fb<<<BB, 64, 0, stream>>>(x, W_ih, W_hh, b_ih, b_hh, W_fc, b_fc, out);
    }
}